// Round 7
// baseline (113.997 us; speedup 1.0000x reference)
//
#include <hip/hip_runtime.h>
#include <math.h>

// Additive attention, MI355X. B=4, Q=K=1024, QSIZE=KSIZE=256, H=32, VDIM=256.
//
// Math: tanh(fq+fk) = 1 - 2/(1 + e^{2fq} e^{2fk}); precompute eq=e^{2fq}, ek=e^{2fk}.
// score = const - 2*sum_h w_h/u_h, u_h = 1 + eq_h ek_h; const cancels in softmax.
// Rational 2-level combine -> 1 rcp per 4 h. Masked k skipped; normalization deferred.
//
// R7: base = R3 (best measured). Single change: batch-INTERLEAVED block mapping
// in attn (b = blockIdx&3). Work per block ~ nvalid[b] (random 1..1024); the old
// contiguous mapping made each batch a contiguous quarter of dispatch order ->
// makespan = worst batch with half the CUs idle in the tail. Interleaving gives
// every CU an equal batch mix -> makespan ~ mean. (R4's XCD-pinning was the
// anti-pattern: it CORRELATED batch with CU; interleave is the fix.)

#define NB 4
#define NQ 1024
#define NK 1024
#define DQK 256
#define NH 32
#define NV 256
#define TQ 8    // q-rows per attn block
#define BLK 512 // attn block size (8 waves)

__device__ __forceinline__ float fast_rcp(float x) { return __builtin_amdgcn_rcpf(x); }

// ---------------------------------------------------------------------------
// Kernel 1: projections + exp(2x). Thread = (row, 4-h group, quarter of dims).
// 8192 rows * 8 hgroups * 4 quarters = 262144 threads = 1024 blocks. (R3 version)
__global__ __launch_bounds__(256) void proj_kernel(
    const float* __restrict__ queries, const float* __restrict__ keys,
    const float* __restrict__ W_q, const float* __restrict__ b_q,
    const float* __restrict__ W_k, const float* __restrict__ b_k,
    float* __restrict__ eq, float* __restrict__ ek)
{
    const int tid     = blockIdx.x * 256 + threadIdx.x;
    const int row     = tid >> 5;            // 0..8191
    const int sub     = tid & 31;
    const int h4      = (sub & 7) * 4;       // h-group
    const int quarter = sub >> 3;            // 0..3 -> dims quarter*64..+63

    const float* src; const float* W; const float* bias; float* dst; int r;
    if (row < NB * NQ) { r = row;           src = queries + (size_t)r * DQK; W = W_q; bias = b_q; dst = eq; }
    else               { r = row - NB * NQ; src = keys    + (size_t)r * DQK; W = W_k; bias = b_k; dst = ek; }

    float a0 = 0.f, a1 = 0.f, a2 = 0.f, a3 = 0.f;
    if (quarter == 0) {
        float4 bv4 = *(const float4*)(bias + h4);
        a0 = bv4.x; a1 = bv4.y; a2 = bv4.z; a3 = bv4.w;
    }
    const int d0 = quarter * 64;
    #pragma unroll 4
    for (int i = d0; i < d0 + 64; i += 4) {
        float4 s  = *(const float4*)(src + i);
        float4 w0 = *(const float4*)(W + (size_t)(i + 0) * NH + h4);
        float4 w1 = *(const float4*)(W + (size_t)(i + 1) * NH + h4);
        float4 w2 = *(const float4*)(W + (size_t)(i + 2) * NH + h4);
        float4 w3 = *(const float4*)(W + (size_t)(i + 3) * NH + h4);
        a0 = fmaf(s.x, w0.x, a0); a1 = fmaf(s.x, w0.y, a1); a2 = fmaf(s.x, w0.z, a2); a3 = fmaf(s.x, w0.w, a3);
        a0 = fmaf(s.y, w1.x, a0); a1 = fmaf(s.y, w1.y, a1); a2 = fmaf(s.y, w1.z, a2); a3 = fmaf(s.y, w1.w, a3);
        a0 = fmaf(s.z, w2.x, a0); a1 = fmaf(s.z, w2.y, a1); a2 = fmaf(s.z, w2.z, a2); a3 = fmaf(s.z, w2.w, a3);
        a0 = fmaf(s.w, w3.x, a0); a1 = fmaf(s.w, w3.y, a1); a2 = fmaf(s.w, w3.z, a2); a3 = fmaf(s.w, w3.w, a3);
    }
    a0 += __shfl_xor(a0, 8, 64);  a1 += __shfl_xor(a1, 8, 64);
    a2 += __shfl_xor(a2, 8, 64);  a3 += __shfl_xor(a3, 8, 64);
    a0 += __shfl_xor(a0, 16, 64); a1 += __shfl_xor(a1, 16, 64);
    a2 += __shfl_xor(a2, 16, 64); a3 += __shfl_xor(a3, 16, 64);
    if (quarter == 0) {
        float4 o;
        o.x = __expf(2.f * a0); o.y = __expf(2.f * a1);
        o.z = __expf(2.f * a2); o.w = __expf(2.f * a3);
        *(float4*)(dst + (size_t)r * NH + h4) = o;
    }
}

// ---------------------------------------------------------------------------
// Kernel 2: fused scores + softmax + weighted sum over values.
// Block = 512 threads (8 waves), handles (b, TQ=8 q-rows). grid = 4*128 = 512.
// Batch-interleaved mapping: b = blockIdx&3 (load balance across CUs).
// Wave w owns k-range [w*kpw, ...) for BOTH score and BMM phases -> no
// inter-wave sync until the final reduction.
__global__ __launch_bounds__(BLK, 4) void attn_kernel(
    const float* __restrict__ eq, const float* __restrict__ ek,
    const float* __restrict__ values, const int* __restrict__ valid_lens,
    const float* __restrict__ w_v, float* __restrict__ out)
{
    __shared__ float s_w[NK][TQ];     // 32 KB: unnormalized exp-weights [k][q]; reused for partials
    __shared__ float s_part[8][TQ];   // per-wave softmax denominator partials

    const int t      = threadIdx.x;
    const int b      = blockIdx.x & 3;          // INTERLEAVED batch
    const int q0     = (blockIdx.x >> 2) * TQ;  // q-block 0..127
    const int nvalid = valid_lens[b];           // [1, 1024]
    const int wave   = t >> 6;
    const int lane   = t & 63;
    const int qi     = lane & 7;
    const int kk     = lane >> 3;               // 0..7

    const int kpw  = (nvalid + 7) >> 3;
    const int kbeg = wave * kpw;
    const int kend = min(nvalid, kbeg + kpw);

    float wv[NH];
    #pragma unroll
    for (int h = 0; h < NH; h += 4) {
        float4 w4 = *(const float4*)(w_v + h);
        wv[h] = w4.x; wv[h+1] = w4.y; wv[h+2] = w4.z; wv[h+3] = w4.w;
    }
    float eqr[NH];
    const float* eqp = eq + (size_t)(b * NQ + q0 + qi) * NH;
    #pragma unroll
    for (int h = 0; h < NH; h += 4) {
        float4 e4 = *(const float4*)(eqp + h);
        eqr[h] = e4.x; eqr[h+1] = e4.y; eqr[h+2] = e4.z; eqr[h+3] = e4.w;
    }

    // ---- scores + exp -> unnormalized weights into this wave's s_w region
    const float* ekbase = ek + (size_t)b * NK * NH;
    float ssum = 0.f;
    for (int k0 = kbeg; k0 < kend; k0 += 8) {
        const int k = k0 + kk;
        if (k < kend) {
            const float* ekp = ekbase + (size_t)k * NH;
            float acc = 0.f;
            #pragma unroll
            for (int h = 0; h < NH; h += 4) {
                float4 e4 = *(const float4*)(ekp + h);
                float u0 = fmaf(eqr[h+0], e4.x, 1.f);
                float u1 = fmaf(eqr[h+1], e4.y, 1.f);
                float u2 = fmaf(eqr[h+2], e4.z, 1.f);
                float u3 = fmaf(eqr[h+3], e4.w, 1.f);
                float d01 = u0 * u1, d23 = u2 * u3;
                float n01 = fmaf(wv[h+0], u1, wv[h+1] * u0);
                float n23 = fmaf(wv[h+2], u3, wv[h+3] * u2);
                float d   = fminf(d01 * d23, 1e38f);   // inf guard
                float n   = fmaf(n01, d23, n23 * d01);
                acc = fmaf(n, fast_rcp(d), acc);
            }
            float e = __expf(-2.f * acc);
            s_w[k][qi] = e;          // lane mod 32 -> 2-way alias = free
            ssum += e;
        }
    }

    // per-wave softmax denominator partial (reduce over kk = lane bits 3..5)
    ssum += __shfl_xor(ssum, 8, 64);
    ssum += __shfl_xor(ssum, 16, 64);
    ssum += __shfl_xor(ssum, 32, 64);
    if (lane < TQ) s_part[wave][lane] = ssum;

    // ---- bmm over the same k-range (weights written by THIS wave: no barrier)
    float4 acc0 = {0,0,0,0}, acc1 = {0,0,0,0}, acc2 = {0,0,0,0}, acc3 = {0,0,0,0};
    float4 acc4 = {0,0,0,0}, acc5 = {0,0,0,0}, acc6 = {0,0,0,0}, acc7 = {0,0,0,0};
    const float* vbase = values + (size_t)b * NK * NV + 4 * lane;

#define FMA4(A, W) A.x = fmaf((W), v.x, A.x); A.y = fmaf((W), v.y, A.y); \
                   A.z = fmaf((W), v.z, A.z); A.w = fmaf((W), v.w, A.w);
    #pragma unroll 4
    for (int k = kbeg; k < kend; k++) {
        float4 v  = *(const float4*)(vbase + (size_t)k * NV);
        float4 w0 = *(const float4*)(&s_w[k][0]);   // wave-uniform broadcast
        float4 w1 = *(const float4*)(&s_w[k][4]);
        FMA4(acc0, w0.x); FMA4(acc1, w0.y); FMA4(acc2, w0.z); FMA4(acc3, w0.w);
        FMA4(acc4, w1.x); FMA4(acc5, w1.y); FMA4(acc6, w1.z); FMA4(acc7, w1.w);
    }
#undef FMA4

    __syncthreads();                 // everyone done with s_w as weights
    float* sred = &s_w[0][0];        // reuse 32 KB as [4 regions][q][256] partials
    float4* p = (float4*)(sred + (size_t)((wave & 3) * TQ) * 256) + lane;
    if (wave < 4) {                  // round A: waves 0..3 write their partials
        p[0*64] = acc0; p[1*64] = acc1; p[2*64] = acc2; p[3*64] = acc3;
        p[4*64] = acc4; p[5*64] = acc5; p[6*64] = acc6; p[7*64] = acc7;
    }
    __syncthreads();
    if (wave >= 4) {                 // round B: waves 4..7 accumulate in place
        float4 x4;
#define ACC4(I, A) x4 = p[I*64]; x4.x += A.x; x4.y += A.y; x4.z += A.z; x4.w += A.w; p[I*64] = x4;
        ACC4(0, acc0); ACC4(1, acc1); ACC4(2, acc2); ACC4(3, acc3);
        ACC4(4, acc4); ACC4(5, acc5); ACC4(6, acc6); ACC4(7, acc7);
#undef ACC4
    }
    __syncthreads();

    // ---- final reduction over 4 regions + deferred normalization.
    const int v  = t & 255;
    const int qh = (t >> 8) * 4;
    float* obase = out + (size_t)(b * NQ + q0) * NV + v;
    #pragma unroll
    for (int jj = 0; jj < 4; jj++) {
        const int q = qh + jj;
        float tot = 0.f;
        #pragma unroll
        for (int w = 0; w < 8; w++) tot += s_part[w][q];
        float rs = fast_rcp(tot);
        float r = sred[(0*TQ + q) * 256 + v] + sred[(1*TQ + q) * 256 + v]
                + sred[(2*TQ + q) * 256 + v] + sred[(3*TQ + q) * 256 + v];
        obase[(size_t)q * NV] = r * rs;
    }
}

// ---------------------------------------------------------------------------
extern "C" void kernel_launch(void* const* d_in, const int* in_sizes, int n_in,
                              void* d_out, int out_size, void* d_ws, size_t ws_size,
                              hipStream_t stream) {
    (void)in_sizes; (void)n_in; (void)out_size; (void)ws_size;
    const float* keys       = (const float*)d_in[0];
    const float* queries    = (const float*)d_in[1];
    const float* values     = (const float*)d_in[2];
    const int*   valid_lens = (const int*)d_in[3];
    const float* W_q        = (const float*)d_in[4];
    const float* b_q        = (const float*)d_in[5];
    const float* W_k        = (const float*)d_in[6];
    const float* b_k        = (const float*)d_in[7];
    const float* w_v        = (const float*)d_in[8];
    // d_in[9] = b_v: cancels in softmax.
    float* out = (float*)d_out;

    float* eq = (float*)d_ws;                       // B*Q*32 floats
    float* ek = eq + (size_t)NB * NQ * NH;          // B*K*32 floats

    proj_kernel<<<dim3(1024), dim3(256), 0, stream>>>(queries, keys, W_q, b_q, W_k, b_k, eq, ek);
    attn_kernel<<<dim3(NB * (NQ / TQ)), dim3(BLK), 0, stream>>>(eq, ek, values, valid_lens, w_v, out);
}

// Round 8
// 107.099 us; speedup vs baseline: 1.0644x; 1.0644x over previous
//
#include <hip/hip_runtime.h>
#include <math.h>

// Additive attention, MI355X. B=4, Q=K=1024, QSIZE=KSIZE=256, H=32, VDIM=256.
//
// Math: tanh(fq+fk) = 1 - 2/(1 + e^{2fq} e^{2fk}); precompute eq=e^{2fq}, ek=e^{2fk}.
// score = const - 2*sum_h w_h/u_h, u_h = 1 + eq_h ek_h; const cancels in softmax.
// Rational 2-level combine -> 1 rcp per 4 h. Masked k skipped; normalization deferred.
//
// R8: base = R3 (measured best: 107.7; R4-R7 deviations all regressed).
// Single change: packed fp32 math (v_pk_fma_f32) in the two FMA-dense loops --
// attn BMM (32 fma -> 16 pk_fma per k) and proj inner step (16 -> 8).
// Score phase's rational tree has cross-component products -> stays scalar.

#define NB 4
#define NQ 1024
#define NK 1024
#define DQK 256
#define NH 32
#define NV 256
#define TQ 8    // q-rows per attn block
#define BLK 512 // attn block size (8 waves)

typedef __attribute__((ext_vector_type(2))) float f32x2;

__device__ __forceinline__ float fast_rcp(float x) { return __builtin_amdgcn_rcpf(x); }

// ---------------------------------------------------------------------------
// Kernel 1: projections + exp(2x). Thread = (row, 4-h group, quarter of dims).
// 8192 rows * 8 hgroups * 4 quarters = 262144 threads = 1024 blocks.
__global__ __launch_bounds__(256) void proj_kernel(
    const float* __restrict__ queries, const float* __restrict__ keys,
    const float* __restrict__ W_q, const float* __restrict__ b_q,
    const float* __restrict__ W_k, const float* __restrict__ b_k,
    float* __restrict__ eq, float* __restrict__ ek)
{
    const int tid     = blockIdx.x * 256 + threadIdx.x;
    const int row     = tid >> 5;            // 0..8191
    const int sub     = tid & 31;
    const int h4      = (sub & 7) * 4;       // h-group
    const int quarter = sub >> 3;            // 0..3 -> dims quarter*64..+63

    const float* src; const float* W; const float* bias; float* dst; int r;
    if (row < NB * NQ) { r = row;           src = queries + (size_t)r * DQK; W = W_q; bias = b_q; dst = eq; }
    else               { r = row - NB * NQ; src = keys    + (size_t)r * DQK; W = W_k; bias = b_k; dst = ek; }

    f32x2 a01 = {0.f, 0.f}, a23 = {0.f, 0.f};
    if (quarter == 0) {
        float4 bv4 = *(const float4*)(bias + h4);
        a01 = (f32x2){bv4.x, bv4.y}; a23 = (f32x2){bv4.z, bv4.w};
    }
    const int d0 = quarter * 64;
    #pragma unroll 4
    for (int i = d0; i < d0 + 64; i += 4) {
        float4 s  = *(const float4*)(src + i);
        float4 w0 = *(const float4*)(W + (size_t)(i + 0) * NH + h4);
        float4 w1 = *(const float4*)(W + (size_t)(i + 1) * NH + h4);
        float4 w2 = *(const float4*)(W + (size_t)(i + 2) * NH + h4);
        float4 w3 = *(const float4*)(W + (size_t)(i + 3) * NH + h4);
#define PSTEP(SC, WR) \
        a01 = __builtin_elementwise_fma((f32x2){SC, SC}, (f32x2){WR.x, WR.y}, a01); \
        a23 = __builtin_elementwise_fma((f32x2){SC, SC}, (f32x2){WR.z, WR.w}, a23);
        PSTEP(s.x, w0) PSTEP(s.y, w1) PSTEP(s.z, w2) PSTEP(s.w, w3)
#undef PSTEP
    }
    float a0 = a01.x, a1 = a01.y, a2 = a23.x, a3 = a23.y;
    a0 += __shfl_xor(a0, 8, 64);  a1 += __shfl_xor(a1, 8, 64);
    a2 += __shfl_xor(a2, 8, 64);  a3 += __shfl_xor(a3, 8, 64);
    a0 += __shfl_xor(a0, 16, 64); a1 += __shfl_xor(a1, 16, 64);
    a2 += __shfl_xor(a2, 16, 64); a3 += __shfl_xor(a3, 16, 64);
    if (quarter == 0) {
        float4 o;
        o.x = __expf(2.f * a0); o.y = __expf(2.f * a1);
        o.z = __expf(2.f * a2); o.w = __expf(2.f * a3);
        *(float4*)(dst + (size_t)r * NH + h4) = o;
    }
}

// ---------------------------------------------------------------------------
// Kernel 2: fused scores + softmax + weighted sum over values.
// Block = 512 threads (8 waves), handles (b, TQ=8 q-rows). grid = 4*128 = 512.
// Contiguous batch mapping (R3, measured best). Wave w owns k-range for BOTH
// score and BMM phases -> no inter-wave sync until the final reduction.
__global__ __launch_bounds__(BLK, 4) void attn_kernel(
    const float* __restrict__ eq, const float* __restrict__ ek,
    const float* __restrict__ values, const int* __restrict__ valid_lens,
    const float* __restrict__ w_v, float* __restrict__ out)
{
    __shared__ float s_w[NK][TQ];     // 32 KB: unnormalized exp-weights [k][q]; reused for partials
    __shared__ float s_part[8][TQ];   // per-wave softmax denominator partials

    const int t      = threadIdx.x;
    const int b      = blockIdx.x >> 7;
    const int q0     = (blockIdx.x & 127) * TQ;
    const int nvalid = valid_lens[b];           // [1, 1024]
    const int wave   = t >> 6;
    const int lane   = t & 63;
    const int qi     = lane & 7;
    const int kk     = lane >> 3;               // 0..7

    const int kpw  = (nvalid + 7) >> 3;
    const int kbeg = wave * kpw;
    const int kend = min(nvalid, kbeg + kpw);

    float wv[NH];
    #pragma unroll
    for (int h = 0; h < NH; h += 4) {
        float4 w4 = *(const float4*)(w_v + h);
        wv[h] = w4.x; wv[h+1] = w4.y; wv[h+2] = w4.z; wv[h+3] = w4.w;
    }
    float eqr[NH];
    const float* eqp = eq + (size_t)(b * NQ + q0 + qi) * NH;
    #pragma unroll
    for (int h = 0; h < NH; h += 4) {
        float4 e4 = *(const float4*)(eqp + h);
        eqr[h] = e4.x; eqr[h+1] = e4.y; eqr[h+2] = e4.z; eqr[h+3] = e4.w;
    }

    // ---- scores + exp -> unnormalized weights into this wave's s_w region
    const float* ekbase = ek + (size_t)b * NK * NH;
    float ssum = 0.f;
    for (int k0 = kbeg; k0 < kend; k0 += 8) {
        const int k = k0 + kk;
        if (k < kend) {
            const float* ekp = ekbase + (size_t)k * NH;
            float acc = 0.f;
            #pragma unroll
            for (int h = 0; h < NH; h += 4) {
                float4 e4 = *(const float4*)(ekp + h);
                float u0 = fmaf(eqr[h+0], e4.x, 1.f);
                float u1 = fmaf(eqr[h+1], e4.y, 1.f);
                float u2 = fmaf(eqr[h+2], e4.z, 1.f);
                float u3 = fmaf(eqr[h+3], e4.w, 1.f);
                float d01 = u0 * u1, d23 = u2 * u3;
                float n01 = fmaf(wv[h+0], u1, wv[h+1] * u0);
                float n23 = fmaf(wv[h+2], u3, wv[h+3] * u2);
                float d   = fminf(d01 * d23, 1e38f);   // inf guard
                float n   = fmaf(n01, d23, n23 * d01);
                acc = fmaf(n, fast_rcp(d), acc);
            }
            float e = __expf(-2.f * acc);
            s_w[k][qi] = e;          // lane mod 32 -> 2-way alias = free
            ssum += e;
        }
    }

    // per-wave softmax denominator partial (reduce over kk = lane bits 3..5)
    ssum += __shfl_xor(ssum, 8, 64);
    ssum += __shfl_xor(ssum, 16, 64);
    ssum += __shfl_xor(ssum, 32, 64);
    if (lane < TQ) s_part[wave][lane] = ssum;

    // ---- bmm over the same k-range (weights written by THIS wave: no barrier)
    // Packed fp32: 16 v_pk_fma_f32 per k instead of 32 v_fma_f32.
    f32x2 l0={0,0},h0={0,0}, l1={0,0},h1={0,0}, l2={0,0},h2={0,0}, l3={0,0},h3={0,0};
    f32x2 l4={0,0},h4={0,0}, l5={0,0},h5={0,0}, l6={0,0},h6={0,0}, l7={0,0},h7={0,0};
    const float* vbase = values + (size_t)b * NK * NV + 4 * lane;

#define PFMA(L, H, W) \
    L = __builtin_elementwise_fma((f32x2){W, W}, vl, L); \
    H = __builtin_elementwise_fma((f32x2){W, W}, vh, H);
    #pragma unroll 4
    for (int k = kbeg; k < kend; k++) {
        float4 v  = *(const float4*)(vbase + (size_t)k * NV);
        f32x2 vl = {v.x, v.y}, vh = {v.z, v.w};
        float4 w0 = *(const float4*)(&s_w[k][0]);   // wave-uniform broadcast
        float4 w1 = *(const float4*)(&s_w[k][4]);
        PFMA(l0, h0, w0.x) PFMA(l1, h1, w0.y) PFMA(l2, h2, w0.z) PFMA(l3, h3, w0.w)
        PFMA(l4, h4, w1.x) PFMA(l5, h5, w1.y) PFMA(l6, h6, w1.z) PFMA(l7, h7, w1.w)
    }
#undef PFMA
    float4 acc0 = {l0.x, l0.y, h0.x, h0.y}, acc1 = {l1.x, l1.y, h1.x, h1.y};
    float4 acc2 = {l2.x, l2.y, h2.x, h2.y}, acc3 = {l3.x, l3.y, h3.x, h3.y};
    float4 acc4 = {l4.x, l4.y, h4.x, h4.y}, acc5 = {l5.x, l5.y, h5.x, h5.y};
    float4 acc6 = {l6.x, l6.y, h6.x, h6.y}, acc7 = {l7.x, l7.y, h7.x, h7.y};

    __syncthreads();                 // everyone done with s_w as weights
    float* sred = &s_w[0][0];        // reuse 32 KB as [4 regions][q][256] partials
    float4* p = (float4*)(sred + (size_t)((wave & 3) * TQ) * 256) + lane;
    if (wave < 4) {                  // round A: waves 0..3 write their partials
        p[0*64] = acc0; p[1*64] = acc1; p[2*64] = acc2; p[3*64] = acc3;
        p[4*64] = acc4; p[5*64] = acc5; p[6*64] = acc6; p[7*64] = acc7;
    }
    __syncthreads();
    if (wave >= 4) {                 // round B: waves 4..7 accumulate in place
        float4 x4;
#define ACC4(I, A) x4 = p[I*64]; x4.x += A.x; x4.y += A.y; x4.z += A.z; x4.w += A.w; p[I*64] = x4;
        ACC4(0, acc0); ACC4(1, acc1); ACC4(2, acc2); ACC4(3, acc3);
        ACC4(4, acc4); ACC4(5, acc5); ACC4(6, acc6); ACC4(7, acc7);
#undef ACC4
    }
    __syncthreads();

    // ---- final reduction over 4 regions + deferred normalization.
    const int v  = t & 255;
    const int qh = (t >> 8) * 4;
    float* obase = out + (size_t)(b * NQ + q0) * NV + v;
    #pragma unroll
    for (int jj = 0; jj < 4; jj++) {
        const int q = qh + jj;
        float tot = 0.f;
        #pragma unroll
        for (int w = 0; w < 8; w++) tot += s_part[w][q];
        float rs = fast_rcp(tot);
        float r = sred[(0*TQ + q) * 256 + v] + sred[(1*TQ + q) * 256 + v]
                + sred[(2*TQ + q) * 256 + v] + sred[(3*TQ + q) * 256 + v];
        obase[(size_t)q * NV] = r * rs;
    }
}

// ---------------------------------------------------------------------------
extern "C" void kernel_launch(void* const* d_in, const int* in_sizes, int n_in,
                              void* d_out, int out_size, void* d_ws, size_t ws_size,
                              hipStream_t stream) {
    (void)in_sizes; (void)n_in; (void)out_size; (void)ws_size;
    const float* keys       = (const float*)d_in[0];
    const float* queries    = (const float*)d_in[1];
    const float* values     = (const float*)d_in[2];
    const int*   valid_lens = (const int*)d_in[3];
    const float* W_q        = (const float*)d_in[4];
    const float* b_q        = (const float*)d_in[5];
    const float* W_k        = (const float*)d_in[6];
    const float* b_k        = (const float*)d_in[7];
    const float* w_v        = (const float*)d_in[8];
    // d_in[9] = b_v: cancels in softmax.
    float* out = (float*)d_out;

    float* eq = (float*)d_ws;                       // B*Q*32 floats
    float* ek = eq + (size_t)NB * NQ * NH;          // B*K*32 floats

    proj_kernel<<<dim3(1024), dim3(256), 0, stream>>>(queries, keys, W_q, b_q, W_k, b_k, eq, ek);
    attn_kernel<<<dim3(NB * (NQ / TQ)), dim3(BLK), 0, stream>>>(eq, ek, values, valid_lens, w_v, out);
}